// Round 2
// baseline (4761.695 us; speedup 1.0000x reference)
//
#include <hip/hip_runtime.h>
#include <hip/hip_bf16.h>
#include <stdint.h>

// GRU decoder: B=128, IN=256, H=512, SEQ=1024, fp32 out.
// R8 = R7 (sentinel-poll dataflow sync) + s_sleep backoff in the retry loop.
// out[] itself is the h-exchange medium: producers store fp32 h via
// system-scope (cache-bypassing) dword stores; out is pre-filled with
// 0xFFFFFFFF (bit30=1, unreachable for |h|<=1) so consumers poll-load
// A-fragments directly with sc0 sc1 dwordx4 loads and validate via bit30 of
// the OR of all dwords. Removes the producer-side vmcnt(0) drain + flag store
// and the consumer-side flag-poll round trip: one one-way IC latency per step
// instead of ~2.5 round trips. No hbuf, no flags, no anti-dependency (each
// out location written exactly once). Backoff throttles IC traffic when a
// validation round fails (R7 risk: 256 waves x 32KB/round unthrottled polling
// could congest the IC and starve producer stores).

constexpr int SEQ = 1024;
constexpr int BATCH = 128;
constexpr int IND = 256;
constexpr int HD = 512;
constexpr int BG = 8;
constexpr int HG = 32;
constexpr int ROWS = BATCH / BG;   // 16
constexpr int NT = 3;              // tiles: r, z, n (16 cols each)

using frag16 = __attribute__((ext_vector_type(8))) short;  // 8 bf16
using f32x4  = __attribute__((ext_vector_type(4))) float;

__device__ __forceinline__ float sigmoid_f(float x) {
    return 1.f / (1.f + __expf(-x));
}
__device__ __forceinline__ float tanh_f(float x) {
    float e = __expf(2.f * x);
    return 1.f - 2.f / (e + 1.f);
}
__device__ __forceinline__ short f2bf(float x) {
    return (short)__bfloat16_as_ushort(__float2bfloat16(x));
}

__global__ __launch_bounds__(64, 1) void gru_kernel(
    const float* __restrict__ x,      // [128, 256]
    const float* __restrict__ w_ih,   // [1536, 256]
    const float* __restrict__ w_hh,   // [1536, 512] fp32 (converted here)
    const float* __restrict__ b_ih,   // [1536]
    const float* __restrict__ b_hh,   // [1536]
    float* __restrict__ out)          // [128, 1024, 512] fp32, pre-filled 0xFF
{
    const int lane = threadIdx.x;
    const int bg = blockIdx.x & 7;    // XCD-aligned batch group (perf only)
    const int hg = blockIdx.x >> 3;
    const int b0 = bg * ROWS;
    const int c0 = hg * 16;
    const int nlo = lane & 15;
    const int quad = lane >> 4;

    // w_hh/gi rows for this lane's three gate tiles
    int gcol[NT];
    gcol[0] = c0 + nlo;           // r
    gcol[1] = HD + c0 + nlo;      // z
    gcol[2] = 2 * HD + c0 + nlo;  // n

    // ---- stage w_hh slice -> LDS in fragment order (once) ----
    __shared__ frag16 ldsB[NT * 16 * 64];  // 48 KB
#pragma unroll
    for (int t = 0; t < NT; ++t) {
        for (int kc = 0; kc < 16; ++kc) {
            const float* src = w_hh + (size_t)gcol[t] * HD + kc * 32 + quad * 8;
            float4 v0 = *(const float4*)src;
            float4 v1 = *(const float4*)(src + 4);
            frag16 f;
            f[0] = f2bf(v0.x); f[1] = f2bf(v0.y); f[2] = f2bf(v0.z); f[3] = f2bf(v0.w);
            f[4] = f2bf(v1.x); f[5] = f2bf(v1.y); f[6] = f2bf(v1.z); f[7] = f2bf(v1.w);
            ldsB[(t * 16 + kc) * 64 + lane] = f;
        }
    }

    // ---- gi = x @ w_ih.T + b_ih (+ b_hh folded for r,z) ----
    float gi[NT][4];
    float bhn = b_hh[gcol[2]];
#pragma unroll
    for (int t = 0; t < NT; ++t) {
        float bi = b_ih[gcol[t]] + ((t < 2) ? b_hh[gcol[t]] : 0.f);
#pragma unroll
        for (int r = 0; r < 4; ++r) gi[t][r] = bi;
    }
    for (int r = 0; r < 4; ++r) {
        const float4* xr = (const float4*)(x + (size_t)(b0 + quad * 4 + r) * IND);
        for (int kc = 0; kc < IND / 4; ++kc) {
            float4 xv = xr[kc];
#pragma unroll
            for (int t = 0; t < NT; ++t) {
                float4 wv = ((const float4*)(w_ih + (size_t)gcol[t] * IND))[kc];
                gi[t][r] += xv.x * wv.x + xv.y * wv.y + xv.z * wv.z + xv.w * wv.w;
            }
        }
    }

    // ---- recurrence ----
    // A-fragment source: lane reads row (b0+nlo), cols quad*8 + kc*32 .. +8
    // of h_{s-1} = out[:, s-1, :].
    const float* pbase = out + (size_t)(b0 + nlo) * (SEQ * HD) + quad * 8;

    float hreg[4];
#pragma unroll
    for (int r = 0; r < 4; ++r) hreg[r] = 0.f;

    for (int s = 0; s < SEQ; ++s) {
        f32x4 C[NT];
#pragma unroll
        for (int t = 0; t < NT; ++t) C[t] = (f32x4){0.f, 0.f, 0.f, 0.f};

        if (s > 0) {
            const float* hrow = pbase + (size_t)(s - 1) * HD;
            f32x4 raw[32];
            for (int tries = 0;; ++tries) {
                if (tries) __builtin_amdgcn_s_sleep(2);  // backoff: ~128 clk
                // issue all 32 L2-bypassing 16B loads (data poll)
#pragma unroll
                for (int kc = 0; kc < 16; ++kc) {
                    asm volatile("global_load_dwordx4 %0, %1, off sc0 sc1"
                                 : "=v"(raw[2 * kc])
                                 : "v"(hrow + kc * 32) : "memory");
                    asm volatile("global_load_dwordx4 %0, %1, off sc0 sc1"
                                 : "=v"(raw[2 * kc + 1])
                                 : "v"(hrow + kc * 32 + 4) : "memory");
                }
                asm volatile("s_waitcnt vmcnt(0)" ::: "memory");
                __builtin_amdgcn_sched_barrier(0);  // keep validate below the wait
                // validate: sentinel (0xFFFFFFFF) has bit30=1; valid h has
                // |h| <= 1 -> exp <= 127 -> bit30=0 (sign bit31 irrelevant).
                unsigned orr = 0u;
#pragma unroll
                for (int i = 0; i < 32; ++i) {
                    orr |= __float_as_uint(raw[i][0]) | __float_as_uint(raw[i][1]) |
                           __float_as_uint(raw[i][2]) | __float_as_uint(raw[i][3]);
                }
                if (__ballot(((orr >> 30) & 1u) == 0u) == ~0ull) break;
            }
            // convert + MFMA
#pragma unroll
            for (int kc = 0; kc < 16; ++kc) {
                frag16 af;
#pragma unroll
                for (int j = 0; j < 4; ++j) {
                    af[j]     = f2bf(raw[2 * kc][j]);
                    af[j + 4] = f2bf(raw[2 * kc + 1][j]);
                }
#pragma unroll
                for (int t = 0; t < NT; ++t) {
                    frag16 bfr = ldsB[(t * 16 + kc) * 64 + lane];
                    C[t] = __builtin_amdgcn_mfma_f32_16x16x32_bf16(af, bfr, C[t], 0, 0, 0);
                }
            }
        }

        // gates + publish (store issue IS the publish; no drain, no flag)
#pragma unroll
        for (int r = 0; r < 4; ++r) {
            float gr  = gi[0][r] + C[0][r];
            float gz  = gi[1][r] + C[1][r];
            float ghn = C[2][r] + bhn;
            float rr = sigmoid_f(gr);
            float zz = sigmoid_f(gz);
            float nn = tanh_f(gi[2][r] + rr * ghn);
            float hn = (1.f - zz) * nn + zz * hreg[r];
            // sentinel-safety clamp: keeps |h| <= 1 so bit30 can never be set
            // (guards the ties-to-even rounding corner). <= 1 ulp @ 1.0.
            hn = fminf(1.f, fmaxf(-1.f, hn));
            hreg[r] = hn;
            int row = b0 + quad * 4 + r;
            unsigned* dst = (unsigned*)out + (size_t)row * (SEQ * HD) +
                            (size_t)s * HD + (c0 + nlo);
            __hip_atomic_store(dst, __float_as_uint(hn),
                               __ATOMIC_RELAXED, __HIP_MEMORY_SCOPE_SYSTEM);
        }
    }
}

extern "C" void kernel_launch(void* const* d_in, const int* in_sizes, int n_in,
                              void* d_out, int out_size, void* d_ws, size_t ws_size,
                              hipStream_t stream) {
    (void)in_sizes; (void)n_in; (void)out_size; (void)d_ws; (void)ws_size;
    const float* x    = (const float*)d_in[0];
    const float* w_ih = (const float*)d_in[1];
    const float* w_hh = (const float*)d_in[2];
    const float* b_ih = (const float*)d_in[3];
    const float* b_hh = (const float*)d_in[4];

    // pre-fill out with the sentinel pattern 0xFFFFFFFF (bit30=1)
    hipMemsetAsync(d_out, 0xFF, (size_t)BATCH * SEQ * HD * sizeof(float), stream);
    gru_kernel<<<BG * HG, 64, 0, stream>>>(x, w_ih, w_hh, b_ih, b_hh, (float*)d_out);
}

// Round 3
// 4139.564 us; speedup vs baseline: 1.1503x; 1.1503x over previous
//
#include <hip/hip_runtime.h>
#include <hip/hip_bf16.h>
#include <stdint.h>

// GRU decoder: B=128, IN=256, H=512, SEQ=1024, fp32 out.
// R9: sentinel-poll dataflow through a SMALL IC-resident bf16 ring (1 MB in
// ws, depth 8), fixing R8's fatal flaw (polling through the 256MB streaming
// out[] thrashed Infinity Cache -> HBM-latency polls, FETCH +124MB).
//  - producers store h_s as packed bf16 pairs (relaxed system-scope dwords)
//    into ring slot s%8; NO drain, NO flag: store issue ends the critical path.
//  - each dword self-validates: |h|<=1 -> bf16 bit14==0, so
//    (dw & 0x40004000)==0 iff both halves are real data. Sentinel=0xFFFFFFFF.
//  - consumers poll-load their MFMA A-fragments (16 x dwordx4 sc0 sc1 = 256B/
//    lane) straight from the ring; the validating load IS the data load, and
//    the bf16 payload feeds MFMA with zero converts.
//  - anti-dependency: WG resets its own tile in slot (s+2)%8 each step.
//    Lockstep bound (each step consumes all peers' prev step) keeps the
//    read-set at slots {s-3..s}%8, disjoint from s+2; reset stores commit at
//    the owner's next poll vmcnt(0), causally before any consumer can poll
//    that slot for the new round -> no stale acceptance, no deadlock.
//  - out stores are non-temporal (stream to HBM, don't evict the ring).

constexpr int SEQ = 1024;
constexpr int BATCH = 128;
constexpr int IND = 256;
constexpr int HD = 512;
constexpr int BG = 8;
constexpr int HG = 32;
constexpr int ROWS = BATCH / BG;   // 16
constexpr int NT = 3;              // tiles: r, z, n (16 cols each)
constexpr int RING_D = 8;
constexpr int SLOT_DW = BATCH * HD / 2;                  // 32768 dwords/slot
constexpr size_t RING_BYTES = (size_t)RING_D * SLOT_DW * 4;  // 1 MB

using frag16 = __attribute__((ext_vector_type(8))) short;  // 8 bf16
using f32x4  = __attribute__((ext_vector_type(4))) float;
using u32x4  = __attribute__((ext_vector_type(4))) unsigned;

__device__ __forceinline__ float sigmoid_f(float x) {
    return 1.f / (1.f + __expf(-x));
}
__device__ __forceinline__ float tanh_f(float x) {
    float e = __expf(2.f * x);
    return 1.f - 2.f / (e + 1.f);
}
__device__ __forceinline__ short f2bf(float x) {
    return (short)__bfloat16_as_ushort(__float2bfloat16(x));
}

__global__ __launch_bounds__(64, 1) void gru_kernel(
    const float* __restrict__ x,      // [128, 256]
    const float* __restrict__ w_ih,   // [1536, 256]
    const float* __restrict__ w_hh,   // [1536, 512] fp32 (converted here)
    const float* __restrict__ b_ih,   // [1536]
    const float* __restrict__ b_hh,   // [1536]
    unsigned* __restrict__ ring,      // RING_D * [128, 512] bf16, 0xFF-filled
    float* __restrict__ out)          // [128, 1024, 512] fp32
{
    const int lane = threadIdx.x;
    const int bg = blockIdx.x & 7;
    const int hg = blockIdx.x >> 3;
    const int b0 = bg * ROWS;
    const int c0 = hg * 16;
    const int nlo = lane & 15;
    const int quad = lane >> 4;

    // w_hh/gi rows for this lane's three gate tiles
    int gcol[NT];
    gcol[0] = c0 + nlo;           // r
    gcol[1] = HD + c0 + nlo;      // z
    gcol[2] = 2 * HD + c0 + nlo;  // n

    // ---- stage w_hh slice -> LDS in fragment order (once) ----
    __shared__ frag16 ldsB[NT * 16 * 64];  // 48 KB
#pragma unroll
    for (int t = 0; t < NT; ++t) {
        for (int kc = 0; kc < 16; ++kc) {
            const float* src = w_hh + (size_t)gcol[t] * HD + kc * 32 + quad * 8;
            float4 v0 = *(const float4*)src;
            float4 v1 = *(const float4*)(src + 4);
            frag16 f;
            f[0] = f2bf(v0.x); f[1] = f2bf(v0.y); f[2] = f2bf(v0.z); f[3] = f2bf(v0.w);
            f[4] = f2bf(v1.x); f[5] = f2bf(v1.y); f[6] = f2bf(v1.z); f[7] = f2bf(v1.w);
            ldsB[(t * 16 + kc) * 64 + lane] = f;
        }
    }

    // ---- gi = x @ w_ih.T + b_ih (+ b_hh folded for r,z) ----
    float gi[NT][4];
    float bhn = b_hh[gcol[2]];
#pragma unroll
    for (int t = 0; t < NT; ++t) {
        float bi = b_ih[gcol[t]] + ((t < 2) ? b_hh[gcol[t]] : 0.f);
#pragma unroll
        for (int r = 0; r < 4; ++r) gi[t][r] = bi;
    }
    for (int r = 0; r < 4; ++r) {
        const float4* xr = (const float4*)(x + (size_t)(b0 + quad * 4 + r) * IND);
        for (int kc = 0; kc < IND / 4; ++kc) {
            float4 xv = xr[kc];
#pragma unroll
            for (int t = 0; t < NT; ++t) {
                float4 wv = ((const float4*)(w_ih + (size_t)gcol[t] * IND))[kc];
                gi[t][r] += xv.x * wv.x + xv.y * wv.y + xv.z * wv.z + xv.w * wv.w;
            }
        }
    }

    // ---- recurrence ----
    // A-fragment source: lane reads bf16 row (b0+nlo), cols kc*32+quad*8..+8
    // of ring slot (s-1)%8. Byte offset within slot: row*1024 + kc*64 + quad*16.
    const size_t arow_byte = (size_t)(b0 + nlo) * (HD * 2) + quad * 16;

    float hreg[4];
#pragma unroll
    for (int r = 0; r < 4; ++r) hreg[r] = 0.f;

    for (int s = 0; s < SEQ; ++s) {
        f32x4 C[NT];
#pragma unroll
        for (int t = 0; t < NT; ++t) C[t] = (f32x4){0.f, 0.f, 0.f, 0.f};

        if (s > 0) {
            const char* lrow =
                (const char*)(ring + ((s - 1) & (RING_D - 1)) * SLOT_DW) + arow_byte;
            u32x4 raw[16];
            for (int tries = 0;; ++tries) {
                if (tries > 1) __builtin_amdgcn_s_sleep(1);  // ~64 clk backoff
                // 16 L2-bypassing 16B loads: the data poll (256 B/lane, IC-hot)
#pragma unroll
                for (int kc = 0; kc < 16; ++kc) {
                    asm volatile("global_load_dwordx4 %0, %1, off sc0 sc1"
                                 : "=v"(raw[kc])
                                 : "v"(lrow + kc * 64) : "memory");
                }
                asm volatile("s_waitcnt vmcnt(0)" ::: "memory");
                __builtin_amdgcn_sched_barrier(0);  // keep validate below the wait
                // valid bf16 pair: |h|<=1 -> bit14 of each half == 0
                unsigned orr = 0u;
#pragma unroll
                for (int kc = 0; kc < 16; ++kc)
                    orr |= raw[kc][0] | raw[kc][1] | raw[kc][2] | raw[kc][3];
                if (__ballot((orr & 0x40004000u) == 0u) == ~0ull) break;
            }
            // MFMA: loaded dwords ARE the bf16 A-fragments (zero converts)
#pragma unroll
            for (int kc = 0; kc < 16; ++kc) {
                union { u32x4 u; frag16 f; } cv;
                cv.u = raw[kc];
#pragma unroll
                for (int t = 0; t < NT; ++t) {
                    frag16 bfr = ldsB[(t * 16 + kc) * 64 + lane];
                    C[t] = __builtin_amdgcn_mfma_f32_16x16x32_bf16(cv.f, bfr, C[t], 0, 0, 0);
                }
            }
        }

        // gates
        float hn[4];
#pragma unroll
        for (int r = 0; r < 4; ++r) {
            float gr  = gi[0][r] + C[0][r];
            float gz  = gi[1][r] + C[1][r];
            float ghn = C[2][r] + bhn;
            float rr = sigmoid_f(gr);
            float zz = sigmoid_f(gz);
            float nn = tanh_f(gi[2][r] + rr * ghn);
            hn[r] = (1.f - zz) * nn + zz * hreg[r];
            hreg[r] = hn[r];
        }

        // publish h_s (bf16 pairs) + reset slot s+2 — store issue IS the
        // publish; the next step's poll vmcnt(0) drains these in background.
        unsigned* wslot = ring + (s & (RING_D - 1)) * SLOT_DW;
        unsigned* rslot = ring + ((s + 2) & (RING_D - 1)) * SLOT_DW;
#pragma unroll
        for (int r = 0; r < 4; ++r) {
            unsigned own = (unsigned)(unsigned short)f2bf(hn[r]);
            unsigned other = (unsigned)__shfl_xor((int)own, 1);
            if ((lane & 1) == 0) {
                int row = b0 + quad * 4 + r;
                unsigned idx = (unsigned)(row * HD + (c0 + nlo)) >> 1;
                __hip_atomic_store(wslot + idx, own | (other << 16),
                                   __ATOMIC_RELAXED, __HIP_MEMORY_SCOPE_SYSTEM);
                __hip_atomic_store(rslot + idx, 0xFFFFFFFFu,
                                   __ATOMIC_RELAXED, __HIP_MEMORY_SCOPE_SYSTEM);
            }
        }
        // out stores: non-temporal, keep the ring IC-resident
#pragma unroll
        for (int r = 0; r < 4; ++r) {
            int row = b0 + quad * 4 + r;
            __builtin_nontemporal_store(
                hn[r], out + (size_t)row * (SEQ * HD) + (size_t)s * HD + (c0 + nlo));
        }
    }
}

extern "C" void kernel_launch(void* const* d_in, const int* in_sizes, int n_in,
                              void* d_out, int out_size, void* d_ws, size_t ws_size,
                              hipStream_t stream) {
    (void)in_sizes; (void)n_in; (void)out_size; (void)ws_size;
    const float* x    = (const float*)d_in[0];
    const float* w_ih = (const float*)d_in[1];
    const float* w_hh = (const float*)d_in[2];
    const float* b_ih = (const float*)d_in[3];
    const float* b_hh = (const float*)d_in[4];

    unsigned* ring = (unsigned*)d_ws;
    // fill the ring with the sentinel pattern (bf16 bit14 set in every half)
    hipMemsetAsync(ring, 0xFF, RING_BYTES, stream);
    gru_kernel<<<BG * HG, 64, 0, stream>>>(x, w_ih, w_hh, b_ih, b_hh, ring,
                                           (float*)d_out);
}

// Round 6
// 2955.509 us; speedup vs baseline: 1.6111x; 1.4006x over previous
//
#include <hip/hip_runtime.h>
#include <hip/hip_bf16.h>
#include <stdint.h>

// GRU decoder: B=128, IN=256, H=512, SEQ=1024, fp32 out.
// R12 = R9 (system-scope sentinel-poll ring, PASSED) + monotone incremental
// polling. R9's deficit vs the flag kernel was poll-traffic contention: every
// retry round re-loaded 16KB/wave through the MALL (256 waves x rounds ->
// ~TB/s of poll traffic saturating the fabric). Per-dword validity is
// MONOTONE within a step window (sentinel -> valid, never back), so retry
// rounds re-load only still-invalid chunks (straggler's 1-2KB, ~8x less).
// Also: no s_sleep (tight poll like the fast flag kernel), and each hn[r] is
// published the moment it's computed (earlier gating of peers).
// All sync constructs are from PASSING kernels only: sc0 sc1 loads (R9),
// relaxed system-scope atomic stores (R6/R9), ring at ws offset 0, 1MB (R9).
//  - ring: depth 8, bf16 pairs, per-dword self-validating (|h|<=1 -> bf16
//    bit14==0; sentinel 0xFFFFFFFF), slot (s+2) reset. Lockstep spread <=1
//    step keeps concurrent resets {s+1..s+3}%8 disjoint from read slot
//    (s-1)%8; reset visibility is ordered by the owner's next poll vmcnt(0)
//    preceding its gating publish (R9-verified causality).
//  - no producer drain, no flags: store issue ends the producer critical path.
//  - out stores non-temporal fp32 (don't pollute MALL).

constexpr int SEQ = 1024;
constexpr int BATCH = 128;
constexpr int IND = 256;
constexpr int HD = 512;
constexpr int BG = 8;
constexpr int HG = 32;
constexpr int ROWS = BATCH / BG;   // 16
constexpr int NT = 3;              // tiles: r, z, n (16 cols each)
constexpr int RING_D = 8;
constexpr int SLOT_DW = BATCH * HD / 2;                      // 32768 dwords
constexpr size_t RING_BYTES = (size_t)RING_D * SLOT_DW * 4;  // 1 MB

using frag16 = __attribute__((ext_vector_type(8))) short;  // 8 bf16
using f32x4  = __attribute__((ext_vector_type(4))) float;
using u32x4  = __attribute__((ext_vector_type(4))) unsigned;

__device__ __forceinline__ float sigmoid_f(float x) {
    return 1.f / (1.f + __expf(-x));
}
__device__ __forceinline__ float tanh_f(float x) {
    float e = __expf(2.f * x);
    return 1.f - 2.f / (e + 1.f);
}
__device__ __forceinline__ short f2bf(float x) {
    return (short)__bfloat16_as_ushort(__float2bfloat16(x));
}

__global__ __launch_bounds__(64, 1) void gru_kernel(
    const float* __restrict__ x,      // [128, 256]
    const float* __restrict__ w_ih,   // [1536, 256]
    const float* __restrict__ w_hh,   // [1536, 512] fp32 (converted here)
    const float* __restrict__ b_ih,   // [1536]
    const float* __restrict__ b_hh,   // [1536]
    unsigned* __restrict__ ring,      // RING_D * [128, 512] bf16, 0xFF-filled
    float* __restrict__ out)          // [128, 1024, 512] fp32
{
    const int lane = threadIdx.x;
    const int bg = blockIdx.x & 7;
    const int hg = blockIdx.x >> 3;
    const int b0 = bg * ROWS;
    const int c0 = hg * 16;
    const int nlo = lane & 15;
    const int quad = lane >> 4;

    int gcol[NT];
    gcol[0] = c0 + nlo;           // r
    gcol[1] = HD + c0 + nlo;      // z
    gcol[2] = 2 * HD + c0 + nlo;  // n

    // ---- stage w_hh slice -> LDS in fragment order (once) ----
    __shared__ frag16 ldsB[NT * 16 * 64];  // 48 KB
#pragma unroll
    for (int t = 0; t < NT; ++t) {
        for (int kc = 0; kc < 16; ++kc) {
            const float* src = w_hh + (size_t)gcol[t] * HD + kc * 32 + quad * 8;
            float4 v0 = *(const float4*)src;
            float4 v1 = *(const float4*)(src + 4);
            frag16 f;
            f[0] = f2bf(v0.x); f[1] = f2bf(v0.y); f[2] = f2bf(v0.z); f[3] = f2bf(v0.w);
            f[4] = f2bf(v1.x); f[5] = f2bf(v1.y); f[6] = f2bf(v1.z); f[7] = f2bf(v1.w);
            ldsB[(t * 16 + kc) * 64 + lane] = f;
        }
    }

    // ---- gi = x @ w_ih.T + b_ih (+ b_hh folded for r,z) ----
    float gi[NT][4];
    float bhn = b_hh[gcol[2]];
#pragma unroll
    for (int t = 0; t < NT; ++t) {
        float bi = b_ih[gcol[t]] + ((t < 2) ? b_hh[gcol[t]] : 0.f);
#pragma unroll
        for (int r = 0; r < 4; ++r) gi[t][r] = bi;
    }
    for (int r = 0; r < 4; ++r) {
        const float4* xr = (const float4*)(x + (size_t)(b0 + quad * 4 + r) * IND);
        for (int kc = 0; kc < IND / 4; ++kc) {
            float4 xv = xr[kc];
#pragma unroll
            for (int t = 0; t < NT; ++t) {
                float4 wv = ((const float4*)(w_ih + (size_t)gcol[t] * IND))[kc];
                gi[t][r] += xv.x * wv.x + xv.y * wv.y + xv.z * wv.z + xv.w * wv.w;
            }
        }
    }

    // ---- recurrence ----
    // A-fragment source: lane reads bf16 row (b0+nlo), cols kc*32+quad*8..+8
    // of ring slot (s-1)%8. Byte offset in slot: row*1024 + kc*64 + quad*16.
    const size_t arow_byte = (size_t)(b0 + nlo) * (HD * 2) + quad * 16;

    float hreg[4] = {0.f, 0.f, 0.f, 0.f};

    for (int s = 0; s < SEQ; ++s) {
        f32x4 C[NT];
#pragma unroll
        for (int t = 0; t < NT; ++t) C[t] = (f32x4){0.f, 0.f, 0.f, 0.f};

        if (s > 0) {
            const char* lrow =
                (const char*)(ring + ((s - 1) & (RING_D - 1)) * SLOT_DW) + arow_byte;
            u32x4 raw[16];
            // monotone incremental poll: re-load only invalid chunks.
            // vmask is lane-uniform (built from ballots) -> uniform branches.
            unsigned vmask = 0u;
            do {
#pragma unroll
                for (int kc = 0; kc < 16; ++kc) {
                    if (!(vmask & (1u << kc))) {
                        asm volatile("global_load_dwordx4 %0, %1, off sc0 sc1"
                                     : "=v"(raw[kc]) : "v"(lrow + kc * 64) : "memory");
                    }
                }
                asm volatile("s_waitcnt vmcnt(0)" ::: "memory");
                __builtin_amdgcn_sched_barrier(0);  // validate below the wait
#pragma unroll
                for (int kc = 0; kc < 16; ++kc) {
                    if (!(vmask & (1u << kc))) {
                        // valid bf16 pair: |h|<=1 -> bit14 of each half == 0
                        unsigned orr = raw[kc][0] | raw[kc][1] | raw[kc][2] | raw[kc][3];
                        if (__ballot((orr & 0x40004000u) == 0u) == ~0ull)
                            vmask |= (1u << kc);
                    }
                }
            } while (vmask != 0xFFFFu);
            // MFMA: loaded dwords ARE the bf16 A-fragments (zero converts)
#pragma unroll
            for (int kc = 0; kc < 16; ++kc) {
                union { u32x4 u; frag16 f; } cv;
                cv.u = raw[kc];
#pragma unroll
                for (int t = 0; t < NT; ++t) {
                    frag16 bfr = ldsB[(t * 16 + kc) * 64 + lane];
                    C[t] = __builtin_amdgcn_mfma_f32_16x16x32_bf16(cv.f, bfr, C[t], 0, 0, 0);
                }
            }
        }

        // gates; publish each hn[r] the moment it's ready (gates peers sooner)
        unsigned* wslot = ring + (s & (RING_D - 1)) * SLOT_DW;
        unsigned* rslot = ring + ((s + 2) & (RING_D - 1)) * SLOT_DW;
        float hn[4];
#pragma unroll
        for (int r = 0; r < 4; ++r) {
            float gr  = gi[0][r] + C[0][r];
            float gz  = gi[1][r] + C[1][r];
            float ghn = C[2][r] + bhn;
            float rr = sigmoid_f(gr);
            float zz = sigmoid_f(gz);
            float nn = tanh_f(gi[2][r] + rr * ghn);
            hn[r] = (1.f - zz) * nn + zz * hreg[r];
            hreg[r] = hn[r];
            unsigned own = (unsigned)(unsigned short)f2bf(hn[r]);
            unsigned other = (unsigned)__shfl_xor((int)own, 1);
            if ((lane & 1) == 0) {
                int row = b0 + quad * 4 + r;
                unsigned idx = (unsigned)(row * HD + (c0 + nlo)) >> 1;
                __hip_atomic_store(wslot + idx, own | (other << 16),
                                   __ATOMIC_RELAXED, __HIP_MEMORY_SCOPE_SYSTEM);
            }
        }
        // reset slot s+2 (restore sentinel for its reuse at step s+7..)
#pragma unroll
        for (int r = 0; r < 4; ++r) {
            if ((lane & 1) == 0) {
                int row = b0 + quad * 4 + r;
                unsigned idx = (unsigned)(row * HD + (c0 + nlo)) >> 1;
                __hip_atomic_store(rslot + idx, 0xFFFFFFFFu,
                                   __ATOMIC_RELAXED, __HIP_MEMORY_SCOPE_SYSTEM);
            }
        }
        // out: non-temporal fp32 stream, don't pollute L2/MALL
#pragma unroll
        for (int r = 0; r < 4; ++r) {
            int row = b0 + quad * 4 + r;
            __builtin_nontemporal_store(
                hn[r], out + (size_t)row * (SEQ * HD) + (size_t)s * HD + (c0 + nlo));
        }
    }
}

extern "C" void kernel_launch(void* const* d_in, const int* in_sizes, int n_in,
                              void* d_out, int out_size, void* d_ws, size_t ws_size,
                              hipStream_t stream) {
    (void)in_sizes; (void)n_in; (void)out_size; (void)ws_size;
    const float* x    = (const float*)d_in[0];
    const float* w_ih = (const float*)d_in[1];
    const float* w_hh = (const float*)d_in[2];
    const float* b_ih = (const float*)d_in[3];
    const float* b_hh = (const float*)d_in[4];

    unsigned* ring = (unsigned*)d_ws;  // R9-proven footprint: 1 MB at offset 0
    hipMemsetAsync(ring, 0xFF, RING_BYTES, stream);  // sentinel fill
    gru_kernel<<<BG * HG, 64, 0, stream>>>(x, w_ih, w_hh, b_ih, b_hh, ring,
                                           (float*)d_out);
}